// Round 10
// baseline (566.720 us; speedup 1.0000x reference)
//
#include <hip/hip_runtime.h>
#include <hip/hip_bf16.h>
#include <math.h>

// ---------------------------------------------------------------------------
// DeepDCNN: emb-gather -> 4x [grouped full-conv + pair-fold + ordered top-k +
// tanh] -> FC.  All fp32.
//
// R10 = R9 with ONE change: layer12_fused declares __launch_bounds__(896, 7).
// R8/R9 lesson: with plain __launch_bounds__(896) the compiler targets 8
// waves/SIMD -> hard 64-VGPR cap; both counting experiments crossed 64 and
// regalloc spilled the whole keys array (WRITE 28.7 -> 240-275MB scratch).
// Occupancy is LDS-bound at 2 blocks/CU = 28 waves/CU = 7 waves/SIMD, which
// permits 73 VGPRs -- declaring (896,7) raises the cap to 72 with NO
// occupancy loss, letting the hybrid-count A/B finally run unconfounded.
// Gates: WRITE_SIZE ~28.7MB / FETCH ~8.6MB (no spill), VGPR 65-72.
//
// Hybrid counting (all selects): per-lane VALU partial count (<=5 bits) +
// 5-ballot binary-sum.  SALU/round 39 -> ~15, VALU/round 34 -> ~90 cyc.
// Theory: ~20 select-waves/CU share ONE scalar unit -> ballot rounds are
// SALU-throughput-bound (~780 cyc/round/CU); hybrid is VALU-bound (~440).
//
// Kept: R4 L1+L2 fusion, R6 layer12 XCD swizzle (FETCH 56->8.6MB), R7 L3
// 2-phase staging (3 blocks/CU) + L3/L4 XCD swizzle.
// ---------------------------------------------------------------------------

#if defined(__has_builtin)
#if __has_builtin(__builtin_amdgcn_ballot_w64)
#define BALLOT64(expr) __builtin_amdgcn_ballot_w64(expr)
#endif
#endif
#ifndef BALLOT64
#define BALLOT64(expr) __ballot(expr)
#endif

__device__ __forceinline__ unsigned f2ord(float f) {
    unsigned u = __float_as_uint(f);
    return (u & 0x80000000u) ? ~u : (u | 0x80000000u);
}
__device__ __forceinline__ float ord2f(unsigned key) {
    unsigned u = (key & 0x80000000u) ? (key & 0x7fffffffu) : ~key;
    return __uint_as_float(u);
}
// tanh via exp + hw rcp: 1 - 2*rcp(e^{2x}+1).  |err| ~1e-7.  Keys are
// pre-tanh so selection ordering is unaffected.
__device__ __forceinline__ float tanh_fast(float x) {
    float e = __expf(2.f * x);
    return 1.f - 2.f * __builtin_amdgcn_rcpf(e + 1.f);
}
__device__ __forceinline__ int mbcnt64(unsigned long long m) {
    return __builtin_amdgcn_mbcnt_hi((unsigned)(m >> 32),
           __builtin_amdgcn_mbcnt_lo((unsigned)m, 0u));
}

// Wave-total of a per-lane 5-bit count: 5 ballots + 5 s_bcnt (SALU-cheap,
// VALU-moderate).  Same construction select_finish uses for prefix sums.
__device__ __forceinline__ int wave_count5(int cnt) {
    int tot = 0;
    #pragma unroll
    for (int b = 0; b < 5; ++b) {
        unsigned long long m = BALLOT64((((cnt >> b) & 1) != 0));
        tot += __popcll(m) << b;
    }
    return tot;
}

// ---- compaction + tanh -> stage (LDS) [-> optional coalesced copy-out] ----
// T = threshold key; stable (earliest ties kept), order-preserving.
// COPY=false: kept values land scattered-compacted in stage and stay there
// (used by the fused kernel, stage = conv-input row in LDS).
// COPY=true: float4 copy stage -> out (k multiple of 4; 16B-aligned rows).
template<int CH, bool COPY>
__device__ __forceinline__ void select_finish(const unsigned* keys, unsigned T,
                                              int k, float* stage,
                                              float* __restrict__ out)
{
    int g = 0, e = 0;
    #pragma unroll
    for (int i = 0; i < CH; ++i) { g += (keys[i] > T); e += (keys[i] == T); }

    int gtBefore = 0, eqBefore = 0, totG = 0;
    #pragma unroll
    for (int b = 0; b < 5; ++b) {     // CH <= 17 < 32 -> 5 bits
        unsigned long long mg = BALLOT64((((g >> b) & 1) != 0));
        unsigned long long me = BALLOT64((((e >> b) & 1) != 0));
        gtBefore += mbcnt64(mg) << b;
        eqBefore += mbcnt64(me) << b;
        totG     += __popcll(mg) << b;
    }
    const int needTies = k - totG;    // # of ==T to keep (earliest)

    int gRun = 0, eRun = 0;
    #pragma unroll
    for (int i = 0; i < CH; ++i) {
        const unsigned key = keys[i];
        const bool isG = key > T;
        const bool isE = key == T;
        const int eIdx = eqBefore + eRun;
        const int dst = gtBefore + gRun + min(eIdx, needTies);
        if (isG || (isE && eIdx < needTies))
            stage[dst] = tanh_fast(ord2f(key));
        gRun += isG; eRun += isE;
    }
    if (COPY) {
        // coalesced vectorized copy-out (same-wave DS ordering makes the
        // scatter-write -> contiguous-read sequence safe without barriers)
        const int lane = threadIdx.x & 63;
        const float4* s4 = (const float4*)stage;
        float4* o4 = (float4*)out;
        #pragma unroll 1
        for (int i = lane; i < (k >> 2); i += 64)
            o4[i] = s4[i];
    }
}

// ---- single-row exact top-k, hybrid counting -----------------------------
// Lane holds contiguous chunk [lane*CH, ...) of the row as order-keys in
// regs; invalid slots MUST be 0 (all finite-float keys are >= 0x00800000).
template<int CH, bool COPY>
__device__ void wave_select1(const unsigned* keys, int k, float* stage,
                             float* __restrict__ out)
{
    unsigned p = 0u;
    int above = 0, buck = 64 * CH;
    #pragma unroll 1
    for (int pos = 31; pos >= 0; --pos) {
        const unsigned t = p | (1u << pos);
        int cnt = 0;
        #pragma unroll
        for (int i = 0; i < CH; ++i)
            cnt += (keys[i] >= t);
        const int c = wave_count5(cnt);
        const int inb = c - above;        // bucket members with bit=1
        const int rem = k - above;
        if (inb >= rem) { p = t; buck = inb; }
        else            { above += inb; buck -= inb; }
        if (buck == k - above) break;
    }
    select_finish<CH, COPY>(keys, p, k, stage, out);
}

// ---- N-row exact top-k, interleaved chains, hybrid counting (L3/L4) ------
template<int N, int CH>
__device__ void wave_selectN(const unsigned (*keys)[CH], int k,
                             float* stage, float* const* outs)
{
    unsigned p[N];
    int above[N], buck[N];
    #pragma unroll
    for (int n = 0; n < N; ++n) { p[n] = 0u; above[n] = 0; buck[n] = 64 * CH; }

    unsigned doneMask = 0;
    const unsigned allDone = (1u << N) - 1u;
    #pragma unroll 1
    for (int pos = 31; pos >= 0; --pos) {
        #pragma unroll
        for (int n = 0; n < N; ++n) {
            if (!((doneMask >> n) & 1u)) {        // wave-uniform branch
                const unsigned t = p[n] | (1u << pos);
                int cnt = 0;
                #pragma unroll
                for (int i = 0; i < CH; ++i)
                    cnt += (keys[n][i] >= t);
                const int c = wave_count5(cnt);
                const int inb = c - above[n];
                const int rem = k - above[n];
                if (inb >= rem) { p[n] = t; buck[n] = inb; }
                else            { above[n] += inb; buck[n] -= inb; }
                if (buck[n] == k - above[n]) doneMask |= (1u << n);
            }
        }
        if (doneMask == allDone) break;
    }
    #pragma unroll
    for (int n = 0; n < N; ++n)
        select_finish<CH, true>(keys[n], p[n], k, stage, outs[n]);
}

// ---------------------------------------------------------------------------
// Fused layers 1+2.  grid (16, 64) -> XCD-swizzled to (j2, b), block 896 =
// 14 waves.  __launch_bounds__(896, 7): occupancy is LDS-bound at 2 blocks/CU
// (28 waves = 7/SIMD); declaring 7 waves/EU raises the VGPR cap 64 -> 72 so
// the keys arrays stay in registers (R8/R9 spilled at the default 64 cap).
// Per block:
//   phase ph=0/1 (L1 group g = 2*j2+ph):
//     - waves 0..9: L1 conv row f1=wav (emb dims 2g,2g+1 from LDS xr),
//       exact top-768 select + tanh written DIRECTLY into z1[wav][4..772)
//     - all 14 waves: L2 partial conv, filter f=wav, input half h=ph
//     - xr restage for ph=1 overlaps the ph=0 accumulation
//   epilogue: top-512 select per filter -> stagebuf -> float4 write to Z2.
// LDS: z1 10x836x4 = 33.4 KB + uni(xr[2][1100] | stagebuf[14][512]) 28.7 KB
//      = 62 KB -> 2 blocks/CU.
// XCD swizzle: all 16 j2-blocks of batch b land on xcd = b>>3.  Per-XCD emb
// working set 8 b x 1024 tok x 256 B = 2 MB < 4 MB L2 (R6: FETCH 56->8.6MB).
// ---------------------------------------------------------------------------
__global__ __launch_bounds__(896, 7) void layer12_fused(
    const int* __restrict__ tokens, const float* __restrict__ emb,
    const float* __restrict__ W1, const float* __restrict__ B1,
    const float* __restrict__ W2, const float* __restrict__ B2,
    float* __restrict__ Z2)
{
    // XCD-aware remap (bijective: 1024 = 8 xcd * 128)
    const int lin = blockIdx.x + (blockIdx.y << 4);
    const int xcd = lin & 7;
    const int q   = lin >> 3;           // 0..127
    const int j2  = q >> 3;             // 0..15
    const int b   = (xcd << 3) + (q & 7); // 0..63; all j2 of b on one xcd

    const int t  = threadIdx.x;
    const int wav  = t >> 6;            // 0..13
    const int lane = t & 63;

    __shared__ __align__(16) float z1[10][836];
    __shared__ __align__(16) float uni[14 * 512]; // xr[2][1100] | stagebuf
    float (*xr)[1100] = reinterpret_cast<float (*)[1100]>(uni);
    const float2* emb2 = (const float2*)emb;

    // zero z1 once: pads stay 0 forever; value region is fully overwritten
    // by each phase's select.
    for (int i = t; i < 10 * 836; i += 896) ((float*)z1)[i] = 0.f;

    // L2 accumulator: filter f = wav, bias = folded pair of halves
    const int f = __builtin_amdgcn_readfirstlane(wav);
    float acc[13];
    {
        const float bias = B2[(2 * j2) * 14 + f] + B2[(2 * j2 + 1) * 14 + f];
        #pragma unroll
        for (int i = 0; i < 13; ++i) acc[i] = bias;
    }
    const int base = lane * 13;

    // stage xr for phase 0 (L1 group g = 2*j2; emb dim pair g)
    {
        const int g = 2 * j2;
        for (int i = t; i < 1100; i += 896) {
            int s = i - 6; float a = 0.f, c = 0.f;
            if (s >= 0 && s < 1024) {
                int tok = tokens[b * 1024 + s];
                float2 v = emb2[(size_t)tok * 32 + g];
                a = v.x; c = v.y;
            }
            xr[0][i] = a; xr[1][i] = c;
        }
    }
    __syncthreads();   // xr(0) + z1 zeros visible

    #pragma unroll 1
    for (int ph = 0; ph < 2; ++ph) {
        const int g = 2 * j2 + ph;

        // ---- L1: conv + select + tanh -> z1 row (waves 0..9) ----
        if (wav < 10) {
            const int f1 = wav;
            float wa[7], wb[7];
            #pragma unroll
            for (int k2 = 0; k2 < 7; ++k2) {
                wa[k2] = W1[(2 * g * 10 + f1) * 7 + k2];
                wb[k2] = W1[((2 * g + 1) * 10 + f1) * 7 + k2];
            }
            const float bias1 = B1[2 * g * 10 + f1] + B1[(2 * g + 1) * 10 + f1];
            const int beg = lane * 17;
            unsigned keys1[17];
            #pragma unroll
            for (int i = 0; i < 17; ++i) {
                float a1 = bias1;
                #pragma unroll
                for (int k2 = 0; k2 < 7; ++k2)
                    a1 += xr[0][beg + i + k2] * wa[k2]
                        + xr[1][beg + i + k2] * wb[k2];
                keys1[i] = (beg + i < 1030) ? f2ord(a1) : 0u;
            }
            wave_select1<17, false>(keys1, 768, &z1[wav][4], nullptr);
        }
        __syncthreads();   // z1(ph) ready; all xr reads of this phase done

        if (ph == 0) {
            // restage xr for phase 1 — overlaps the h=0 accumulation below
            const int g1 = 2 * j2 + 1;
            for (int i = t; i < 1100; i += 896) {
                int s = i - 6; float a = 0.f, c = 0.f;
                if (s >= 0 && s < 1024) {
                    int tok = tokens[b * 1024 + s];
                    float2 v = emb2[(size_t)tok * 32 + g1];
                    a = v.x; c = v.y;
                }
                xr[0][i] = a; xr[1][i] = c;
            }
        }

        // ---- L2 partial conv: all 14 waves, filter f, half h=ph ----
        {
            const float* Wp0 = W2 + (size_t)((2 * j2 + ph) * 14 + f) * 10 * 5;
            #pragma unroll 1
            for (int r = 0; r < 10; ++r) {
                float win[17];
                #pragma unroll
                for (int p = 0; p < 17; ++p) win[p] = z1[r][base + p];
                const float* Wp = Wp0 + r * 5;
                #pragma unroll
                for (int k2 = 0; k2 < 5; ++k2) {
                    const float w0 = Wp[k2];
                    #pragma unroll
                    for (int i = 0; i < 13; ++i)
                        acc[i] = fmaf(win[i + k2], w0, acc[i]);
                }
            }
        }
        if (ph == 0) __syncthreads();  // xr(1) staged & z1(0) fully consumed
    }

    // ---- L2 select: one chain per wave, k=512 -> Z2 row ----
    // stagebuf aliases xr; last xr read was phase-1 L1 conv, separated from
    // here by the phase-1 post-L1 barrier.
    unsigned keys2[13];
    #pragma unroll
    for (int i = 0; i < 13; ++i)
        keys2[i] = (base + i < 772) ? f2ord(acc[i]) : 0u;
    float* stage = uni + wav * 512;
    float* outp = Z2 + ((size_t)b * 224 + (size_t)j2 * 14 + f) * 512;
    wave_select1<13, true>(keys2, 512, stage, outp);
}

// ---------------------------------------------------------------------------
// Fused conv + fold + select + tanh (layers 3-4).
// grid (GRIDJ j, 64 b) -> XCD-swizzled so all j-blocks of batch b land on
// xcd = b>>3 (matches layer12's Z2/Z3 placement -> producer-L2 hits).
// Wave w computes output rows (filters) f = 2w, 2w+1 (length SOUT), then
// dual-chain selects top-KSEL of each.
// ---------------------------------------------------------------------------
template <int IPG, int NF, int K, int SIN, int SOUT, int KSEL, int NW, int CH,
          int PHASES, int GRIDJ>
__global__ __launch_bounds__(NW * 64) void conv_fold_select_kernel(
    const float* __restrict__ X, const float* __restrict__ W,
    const float* __restrict__ Bias, float* __restrict__ Z,
    int Cin, int Cfold)
{
    static_assert(NF == 2 * NW, "2 filters per wave");
    static_assert(64 * CH >= SOUT, "chunk covers row");
    constexpr int W2 = 64 * CH + K - 1;     // padded LDS row width
    constexpr int RS = 2 * IPG / PHASES;    // rows staged per phase

    const int t = threadIdx.x;
    // XCD-aware remap (bijective: GRIDJ*64 = 8 xcd * (GRIDJ*8))
    const int lin = blockIdx.x + blockIdx.y * GRIDJ;
    const int xcd = lin & 7;
    const int q   = lin >> 3;
    const int j   = q >> 3;                 // 0..GRIDJ-1
    const int b   = (xcd << 3) + (q & 7);   // all j of b on one xcd
    const int wav = t >> 6, lane = t & 63;

    __shared__ __align__(16) float xs[RS][W2];
    __shared__ __align__(16) float stagebuf[NW][KSEL];

    const float* Xb = X + ((size_t)b * Cin + (size_t)(2 * j) * IPG) * SIN;

    const int f0 = __builtin_amdgcn_readfirstlane(2 * wav);
    float acc0[CH], acc1[CH];
    {
        float bias0 = Bias[2 * j * NF + f0]     + Bias[(2 * j + 1) * NF + f0];
        float bias1 = Bias[2 * j * NF + f0 + 1] + Bias[(2 * j + 1) * NF + f0 + 1];
        #pragma unroll
        for (int i = 0; i < CH; ++i) { acc0[i] = bias0; acc1[i] = bias1; }
    }
    const int base = lane * CH;

    #pragma unroll 1
    for (int ph = 0; ph < PHASES; ++ph) {
        if (ph) __syncthreads();            // prior phase's reads done
        for (int idx = t; idx < RS * W2; idx += NW * 64) {
            int r = idx / W2, p = idx - r * W2;
            int sg = p - (K - 1);
            int gr = ph * RS + r;
            xs[r][p] = (sg >= 0 && sg < SIN) ? Xb[(size_t)gr * SIN + sg] : 0.f;
        }
        __syncthreads();

        int h = (ph * RS) / IPG, c = (ph * RS) % IPG;
        #pragma unroll 1
        for (int r = 0; r < RS; ++r) {
            float win[CH + K - 1];
            #pragma unroll
            for (int p = 0; p < CH + K - 1; ++p)
                win[p] = xs[r][base + p];
            const float* Wp = W + ((size_t)((2 * j + h) * NF + f0) * IPG + c) * K;
            #pragma unroll
            for (int k2 = 0; k2 < K; ++k2) {
                const float w0 = Wp[k2];
                const float w1 = Wp[(size_t)IPG * K + k2];
                #pragma unroll
                for (int i = 0; i < CH; ++i) {
                    acc0[i] = fmaf(win[i + k2], w0, acc0[i]);
                    acc1[i] = fmaf(win[i + k2], w1, acc1[i]);
                }
            }
            if (++c == IPG) { c = 0; ++h; }
        }
    }

    unsigned keys[2][CH];
    #pragma unroll
    for (int i = 0; i < CH; ++i) {
        keys[0][i] = (base + i < SOUT) ? f2ord(acc0[i]) : 0u;
        keys[1][i] = (base + i < SOUT) ? f2ord(acc1[i]) : 0u;
    }
    const size_t orow = (size_t)b * Cfold + (size_t)j * NF;
    float* outs[2] = { Z + (orow + f0) * (size_t)KSEL,
                       Z + (orow + f0 + 1) * (size_t)KSEL };
    wave_selectN<2, CH>(keys, KSEL, stagebuf[wav], outs);
}

// ---------------------------------------------------------------------------
// FC: (64,352) @ (6,352)^T + b
// ---------------------------------------------------------------------------
__global__ __launch_bounds__(192) void fc_kernel(
    const float* __restrict__ Z, const float* __restrict__ Wf,
    const float* __restrict__ bf, float* __restrict__ out)
{
    int g = blockIdx.x * blockDim.x + threadIdx.x;
    if (g >= 64 * 6) return;
    int b = g / 6, c = g % 6;
    float acc = bf[c];
    const float* zr = Z + b * 352;
    const float* wr = Wf + c * 352;
    for (int i = 0; i < 352; ++i) acc += zr[i] * wr[i];
    out[g] = acc;
}

extern "C" void kernel_launch(void* const* d_in, const int* in_sizes, int n_in,
                              void* d_out, int out_size, void* d_ws, size_t ws_size,
                              hipStream_t stream)
{
    const int*   tokens = (const int*)  d_in[0];
    const float* emb    = (const float*)d_in[1];
    const float* w1     = (const float*)d_in[2];
    const float* b1     = (const float*)d_in[3];
    const float* w2     = (const float*)d_in[4];
    const float* b2     = (const float*)d_in[5];
    const float* w3     = (const float*)d_in[6];
    const float* b3     = (const float*)d_in[7];
    const float* w4     = (const float*)d_in[8];
    const float* b4     = (const float*)d_in[9];
    const float* fcw    = (const float*)d_in[10];
    const float* fcb    = (const float*)d_in[11];
    float* out = (float*)d_out;
    float* ws  = (float*)d_ws;

    // workspace layout (floats) — Z1 no longer exists (fused away):
    //  Z2 [15728640, 23068672)   64*224*512  (29 MB)
    //  Z3 [0,         2359296)   64*144*256
    //  Z4 [2359296,   2381824)   64*88*4
    float* Z2 = ws + 15728640;
    float* Z3 = ws;
    float* Z4 = ws + 2359296;

    // L1+L2 fused: emb gather + pair conv K=7 + fold + top768 + tanh (LDS)
    //              + grouped conv IPG=10 K=5 + fold + top512 + tanh -> Z2
    layer12_fused<<<dim3(16, 64), 896, 0, stream>>>(
        tokens, emb, w1, b1, w2, b2, Z2);

    // L3: IPG=14 NF=18 K=5  512->516, keep 256.  NW=9, CH=9, 2-phase
    //     (LDS 41.7KB -> 3 blocks/CU), XCD swizzle GRIDJ=8
    conv_fold_select_kernel<14, 18, 5, 512, 516, 256, 9, 9, 2, 8>
        <<<dim3(8, 64), 9 * 64, 0, stream>>>(Z2, w3, b3, Z3, 224, 144);

    // L4: IPG=18 NF=22 K=3  256->258, keep 4.  NW=11, CH=5, 1-phase,
    //     XCD swizzle GRIDJ=4
    conv_fold_select_kernel<18, 22, 3, 256, 258, 4, 11, 5, 1, 4>
        <<<dim3(4, 64), 11 * 64, 0, stream>>>(Z3, w4, b4, Z4, 144, 88);

    fc_kernel<<<2, 192, 0, stream>>>(Z4, fcw, fcb, out);
}

// Round 11
// 324.867 us; speedup vs baseline: 1.7445x; 1.7445x over previous
//
#include <hip/hip_runtime.h>
#include <hip/hip_bf16.h>
#include <math.h>

// ---------------------------------------------------------------------------
// DeepDCNN: emb-gather -> 4x [grouped full-conv + pair-fold + ordered top-k +
// tanh] -> FC.  All fp32.
//
// R11 = R7 base (310.9us best; plain __launch_bounds__(896), ballot selects
// in L3/L4) + ONE work-removal in layer12: the radix-select threshold search
// is replaced by a 4-pass byte-radix rank search over per-wave LDS
// histograms (~300 inst vs ~1400 for the 25-round ballot search).  The
// search returns the EXACT k-th-largest key T; select_finish (unchanged)
// reconstructs counts/ties from T, so selection semantics are identical.
// Histograms live inside each wave's own stage region (no extra LDS, no new
// barriers): z1 row words [0,256) for the L1 selects (leading 4-word pad
// re-zeroed after finish), stagebuf slot for the final select.
//
// R8-R10 lesson (closed): select-count rewrites + launch-bounds hints kept
// tripping the 64-VGPR regalloc cliff -> wholesale keys-array spill
// (WRITE 28.7 -> 240-700MB).  Gates this round: VGPR<=64, WRITE~28.7MB.
// R1-R7 lesson: only removed instructions/traffic move the clean total
// (power/clock-capped); pipe-shuffling is neutral.
// ---------------------------------------------------------------------------

#if defined(__has_builtin)
#if __has_builtin(__builtin_amdgcn_ballot_w64)
#define BALLOT64(expr) __builtin_amdgcn_ballot_w64(expr)
#endif
#endif
#ifndef BALLOT64
#define BALLOT64(expr) __ballot(expr)
#endif

__device__ __forceinline__ unsigned f2ord(float f) {
    unsigned u = __float_as_uint(f);
    return (u & 0x80000000u) ? ~u : (u | 0x80000000u);
}
__device__ __forceinline__ float ord2f(unsigned key) {
    unsigned u = (key & 0x80000000u) ? (key & 0x7fffffffu) : ~key;
    return __uint_as_float(u);
}
// tanh via exp + hw rcp: 1 - 2*rcp(e^{2x}+1).  |err| ~1e-7.  Keys are
// pre-tanh so selection ordering is unaffected.
__device__ __forceinline__ float tanh_fast(float x) {
    float e = __expf(2.f * x);
    return 1.f - 2.f * __builtin_amdgcn_rcpf(e + 1.f);
}
__device__ __forceinline__ int mbcnt64(unsigned long long m) {
    return __builtin_amdgcn_mbcnt_hi((unsigned)(m >> 32),
           __builtin_amdgcn_mbcnt_lo((unsigned)m, 0u));
}

// Inclusive 64-lane prefix sum (canonical gfx9 DPP ladder); also returns the
// wave total (readlane 63, wave-uniform).  Same sequence as the R2 wave_sum64
// (correctness-proven); intermediate lanes carry the inclusive scan.
__device__ __forceinline__ unsigned wave_scan_incl(unsigned v, unsigned& tot) {
    v += __builtin_amdgcn_update_dpp(0, v, 0x111, 0xf, 0xf, true);  // shr:1
    v += __builtin_amdgcn_update_dpp(0, v, 0x112, 0xf, 0xf, true);  // shr:2
    v += __builtin_amdgcn_update_dpp(0, v, 0x114, 0xf, 0xf, true);  // shr:4
    v += __builtin_amdgcn_update_dpp(0, v, 0x118, 0xf, 0xf, true);  // shr:8
    v += __builtin_amdgcn_update_dpp(0, v, 0x142, 0xa, 0xf, false); // bcast:15
    v += __builtin_amdgcn_update_dpp(0, v, 0x143, 0xc, 0xf, false); // bcast:31
    tot = __builtin_amdgcn_readlane(v, 63);
    return v;
}

// ---- compaction + tanh -> stage (LDS) [-> optional coalesced copy-out] ----
// T = threshold key; stable (earliest ties kept), order-preserving.
// COPY=false: kept values land scattered-compacted in stage and stay there
// (used by the fused kernel, stage = conv-input row in LDS).
// COPY=true: float4 copy stage -> out (k multiple of 4; 16B-aligned rows).
template<int CH, bool COPY>
__device__ __forceinline__ void select_finish(const unsigned* keys, unsigned T,
                                              int k, float* stage,
                                              float* __restrict__ out)
{
    int g = 0, e = 0;
    #pragma unroll
    for (int i = 0; i < CH; ++i) { g += (keys[i] > T); e += (keys[i] == T); }

    int gtBefore = 0, eqBefore = 0, totG = 0;
    #pragma unroll
    for (int b = 0; b < 5; ++b) {     // CH <= 17 < 32 -> 5 bits
        unsigned long long mg = BALLOT64((((g >> b) & 1) != 0));
        unsigned long long me = BALLOT64((((e >> b) & 1) != 0));
        gtBefore += mbcnt64(mg) << b;
        eqBefore += mbcnt64(me) << b;
        totG     += __popcll(mg) << b;
    }
    const int needTies = k - totG;    // # of ==T to keep (earliest)

    int gRun = 0, eRun = 0;
    #pragma unroll
    for (int i = 0; i < CH; ++i) {
        const unsigned key = keys[i];
        const bool isG = key > T;
        const bool isE = key == T;
        const int eIdx = eqBefore + eRun;
        const int dst = gtBefore + gRun + min(eIdx, needTies);
        if (isG || (isE && eIdx < needTies))
            stage[dst] = tanh_fast(ord2f(key));
        gRun += isG; eRun += isE;
    }
    if (COPY) {
        // coalesced vectorized copy-out (same-wave DS ordering makes the
        // scatter-write -> contiguous-read sequence safe without barriers)
        const int lane = threadIdx.x & 63;
        const float4* s4 = (const float4*)stage;
        float4* o4 = (float4*)out;
        #pragma unroll 1
        for (int i = lane; i < (k >> 2); i += 64)
            o4[i] = s4[i];
    }
}

// ---- exact k-th-largest key via 4-pass byte-radix rank search ------------
// keys: lane-local chunk of the row (invalid slots 0).  hist: per-WAVE LDS
// region of 256 unsigned (16B-aligned); dead scratch afterwards.
// Pass p resolves byte p (MSB first): histogram the candidate keys' byte,
// suffix-rank from the top, descend into the bucket containing rank kk.
// All DS ops are same-wave (issue-ordered); one lgkmcnt(0) before the read.
template<int CH>
__device__ unsigned radix_threshold(const unsigned* keys, int k,
                                    unsigned* hist)
{
    const int lane = threadIdx.x & 63;
    unsigned prefix = 0u;
    int kk = k;
    #pragma unroll
    for (int pass = 0; pass < 4; ++pass) {
        const int shift = 24 - 8 * pass;
        const int sh2 = (pass == 0) ? 0 : shift + 8;   // bits above this byte
        // zero my 4 buckets (lane l owns buckets 4l..4l+3)
        *reinterpret_cast<uint4*>(hist + 4 * lane) = make_uint4(0u, 0u, 0u, 0u);
        // populate: keys whose resolved high bytes match prefix
        #pragma unroll
        for (int i = 0; i < CH; ++i) {
            const unsigned key = keys[i];
            const bool m = (pass == 0) || ((key >> sh2) == prefix);
            if (m) atomicAdd(&hist[(key >> shift) & 0xFFu], 1u);
        }
        asm volatile("s_waitcnt lgkmcnt(0)" ::: "memory");
        const uint4 c = *reinterpret_cast<const uint4*>(hist + 4 * lane);

        // suffix ranks: S(b) = #candidates in buckets > b
        unsigned tot;
        const unsigned incl = wave_scan_incl(c.x + c.y + c.z + c.w, tot);
        const unsigned Sl = tot - incl;        // buckets in lanes > l
        const unsigned S3 = Sl;
        const unsigned S2 = S3 + c.w;
        const unsigned S1 = S2 + c.z;
        const unsigned S0 = S1 + c.y;

        int fb = -1; unsigned fS = 0u;         // exactly one lane/bucket hits
        if ((int)S0 < kk && kk <= (int)(S0 + c.x)) { fb = 4 * lane + 0; fS = S0; }
        if ((int)S1 < kk && kk <= (int)(S1 + c.y)) { fb = 4 * lane + 1; fS = S1; }
        if ((int)S2 < kk && kk <= (int)(S2 + c.z)) { fb = 4 * lane + 2; fS = S2; }
        if ((int)S3 < kk && kk <= (int)(S3 + c.w)) { fb = 4 * lane + 3; fS = S3; }

        const unsigned long long mv = BALLOT64(fb >= 0);
        const int src = (int)__ffsll(mv) - 1;
        const int B = __shfl(fb, src);
        const unsigned S = (unsigned)__shfl((int)fS, src);
        prefix = (prefix << 8) | (unsigned)B;
        kk -= (int)S;                          // rank within chosen bucket
    }
    return prefix;                             // exact k-th-largest key
}

// ---- N-row exact top-k, interleaved ballot chains (conv L3/L4, N=2) ------
template<int N, int CH>
__device__ void wave_selectN_ballot(const unsigned (*keys)[CH], int k,
                                    float* stage, float* const* outs)
{
    unsigned p[N];
    int above[N], buck[N];
    #pragma unroll
    for (int n = 0; n < N; ++n) { p[n] = 0u; above[n] = 0; buck[n] = 64 * CH; }

    unsigned doneMask = 0;
    const unsigned allDone = (1u << N) - 1u;
    #pragma unroll 1
    for (int pos = 31; pos >= 0; --pos) {
        #pragma unroll
        for (int n = 0; n < N; ++n) {
            if (!((doneMask >> n) & 1u)) {        // wave-uniform branch
                const unsigned t = p[n] | (1u << pos);
                int c = 0;
                #pragma unroll
                for (int i = 0; i < CH; ++i)
                    c += __popcll(BALLOT64((keys[n][i] >= t)));
                const int inb = c - above[n];
                const int rem = k - above[n];
                if (inb >= rem) { p[n] = t; buck[n] = inb; }
                else            { above[n] += inb; buck[n] -= inb; }
                if (buck[n] == k - above[n]) doneMask |= (1u << n);
            }
        }
        if (doneMask == allDone) break;
    }
    #pragma unroll
    for (int n = 0; n < N; ++n)
        select_finish<CH, true>(keys[n], p[n], k, stage, outs[n]);
}

// ---------------------------------------------------------------------------
// Fused layers 1+2.  grid (16, 64) -> XCD-swizzled to (j2, b), block 896 =
// 14 waves.
// Per block:
//   phase ph=0/1 (L1 group g = 2*j2+ph):
//     - waves 0..9: L1 conv row f1=wav (emb dims 2g,2g+1 from LDS xr),
//       radix-rank search (hist = own z1 row words [0,256)) + finish writes
//       tanh'd keepers DIRECTLY into z1[wav][4..772); pad words [0,4)
//       re-zeroed after (hist scribbled them)
//     - all 14 waves: L2 partial conv, filter f=wav, input half h=ph
//     - xr restage for ph=1 overlaps the ph=0 accumulation
//   epilogue: radix-rank top-512 per filter (hist = own stagebuf slot) ->
//   stagebuf -> float4 write to Z2.
// LDS: z1 10x836x4 = 33.4 KB + uni(xr[2][1100] | stagebuf[14][512]) 28.7 KB
//      = 62 KB -> 2 blocks/CU.  Histograms alias stage regions: zero extra.
// XCD swizzle: all 16 j2-blocks of batch b land on xcd = b>>3.  Per-XCD emb
// working set 8 b x 1024 tok x 256 B = 2 MB < 4 MB L2 (R6: FETCH 56->8.6MB).
// ---------------------------------------------------------------------------
__global__ __launch_bounds__(896) void layer12_fused(
    const int* __restrict__ tokens, const float* __restrict__ emb,
    const float* __restrict__ W1, const float* __restrict__ B1,
    const float* __restrict__ W2, const float* __restrict__ B2,
    float* __restrict__ Z2)
{
    // XCD-aware remap (bijective: 1024 = 8 xcd * 128)
    const int lin = blockIdx.x + (blockIdx.y << 4);
    const int xcd = lin & 7;
    const int q   = lin >> 3;           // 0..127
    const int j2  = q >> 3;             // 0..15
    const int b   = (xcd << 3) + (q & 7); // 0..63; all j2 of b on one xcd

    const int t  = threadIdx.x;
    const int wav  = t >> 6;            // 0..13
    const int lane = t & 63;

    __shared__ __align__(16) float z1[10][836];
    __shared__ __align__(16) float uni[14 * 512]; // xr[2][1100] | stagebuf
    float (*xr)[1100] = reinterpret_cast<float (*)[1100]>(uni);
    const float2* emb2 = (const float2*)emb;

    // zero z1 once: pads stay 0 except where hist scribbles (re-zeroed);
    // value region is fully overwritten by each phase's select.
    for (int i = t; i < 10 * 836; i += 896) ((float*)z1)[i] = 0.f;

    // L2 accumulator: filter f = wav, bias = folded pair of halves
    const int f = __builtin_amdgcn_readfirstlane(wav);
    float acc[13];
    {
        const float bias = B2[(2 * j2) * 14 + f] + B2[(2 * j2 + 1) * 14 + f];
        #pragma unroll
        for (int i = 0; i < 13; ++i) acc[i] = bias;
    }
    const int base = lane * 13;

    // stage xr for phase 0 (L1 group g = 2*j2; emb dim pair g)
    {
        const int g = 2 * j2;
        for (int i = t; i < 1100; i += 896) {
            int s = i - 6; float a = 0.f, c = 0.f;
            if (s >= 0 && s < 1024) {
                int tok = tokens[b * 1024 + s];
                float2 v = emb2[(size_t)tok * 32 + g];
                a = v.x; c = v.y;
            }
            xr[0][i] = a; xr[1][i] = c;
        }
    }
    __syncthreads();   // xr(0) + z1 zeros visible

    #pragma unroll 1
    for (int ph = 0; ph < 2; ++ph) {
        const int g = 2 * j2 + ph;

        // ---- L1: conv + radix select + tanh -> z1 row (waves 0..9) ----
        if (wav < 10) {
            const int f1 = wav;
            float wa[7], wb[7];
            #pragma unroll
            for (int k2 = 0; k2 < 7; ++k2) {
                wa[k2] = W1[(2 * g * 10 + f1) * 7 + k2];
                wb[k2] = W1[((2 * g + 1) * 10 + f1) * 7 + k2];
            }
            const float bias1 = B1[2 * g * 10 + f1] + B1[(2 * g + 1) * 10 + f1];
            const int beg = lane * 17;
            unsigned keys1[17];
            #pragma unroll
            for (int i = 0; i < 17; ++i) {
                float a1 = bias1;
                #pragma unroll
                for (int k2 = 0; k2 < 7; ++k2)
                    a1 += xr[0][beg + i + k2] * wa[k2]
                        + xr[1][beg + i + k2] * wb[k2];
                keys1[i] = (beg + i < 1030) ? f2ord(a1) : 0u;
            }
            // hist = own row's first 256 words (dead until finish rewrites)
            unsigned* hist = reinterpret_cast<unsigned*>(&z1[wav][0]);
            const unsigned T = radix_threshold<17>(keys1, 768, hist);
            select_finish<17, false>(keys1, T, 768, &z1[wav][4], nullptr);
            // re-zero the 4 leading pad words the histogram scribbled
            if (lane == 0)
                *reinterpret_cast<uint4*>(&z1[wav][0]) =
                    make_uint4(0u, 0u, 0u, 0u);
        }
        __syncthreads();   // z1(ph) ready; all xr reads of this phase done

        if (ph == 0) {
            // restage xr for phase 1 — overlaps the h=0 accumulation below
            const int g1 = 2 * j2 + 1;
            for (int i = t; i < 1100; i += 896) {
                int s = i - 6; float a = 0.f, c = 0.f;
                if (s >= 0 && s < 1024) {
                    int tok = tokens[b * 1024 + s];
                    float2 v = emb2[(size_t)tok * 32 + g1];
                    a = v.x; c = v.y;
                }
                xr[0][i] = a; xr[1][i] = c;
            }
        }

        // ---- L2 partial conv: all 14 waves, filter f, half h=ph ----
        {
            const float* Wp0 = W2 + (size_t)((2 * j2 + ph) * 14 + f) * 10 * 5;
            #pragma unroll 1
            for (int r = 0; r < 10; ++r) {
                float win[17];
                #pragma unroll
                for (int p = 0; p < 17; ++p) win[p] = z1[r][base + p];
                const float* Wp = Wp0 + r * 5;
                #pragma unroll
                for (int k2 = 0; k2 < 5; ++k2) {
                    const float w0 = Wp[k2];
                    #pragma unroll
                    for (int i = 0; i < 13; ++i)
                        acc[i] = fmaf(win[i + k2], w0, acc[i]);
                }
            }
        }
        if (ph == 0) __syncthreads();  // xr(1) staged & z1(0) fully consumed
    }

    // ---- L2 select: radix-rank search, hist in own stage slot -> Z2 ----
    // stagebuf aliases xr; last xr read (ph1 key computation) is separated
    // from here by the ph1 post-select barrier.  hist occupies the first 256
    // words of this wave's OWN stage slot; finish overwrites all 512.
    unsigned keys2[13];
    #pragma unroll
    for (int i = 0; i < 13; ++i)
        keys2[i] = (base + i < 772) ? f2ord(acc[i]) : 0u;
    float* stage = uni + wav * 512;
    unsigned* hist2 = reinterpret_cast<unsigned*>(stage);
    const unsigned T2 = radix_threshold<13>(keys2, 512, hist2);
    float* outp = Z2 + ((size_t)b * 224 + (size_t)j2 * 14 + f) * 512;
    select_finish<13, true>(keys2, T2, 512, stage, outp);
}

// ---------------------------------------------------------------------------
// Fused conv + fold + select + tanh (layers 3-4).
// grid (GRIDJ j, 64 b) -> XCD-swizzled so all j-blocks of batch b land on
// xcd = b>>3 (matches layer12's Z2/Z3 placement -> producer-L2 hits).
// Wave w computes output rows (filters) f = 2w, 2w+1 (length SOUT), then
// dual-chain selects top-KSEL of each.
// ---------------------------------------------------------------------------
template <int IPG, int NF, int K, int SIN, int SOUT, int KSEL, int NW, int CH,
          int PHASES, int GRIDJ>
__global__ __launch_bounds__(NW * 64) void conv_fold_select_kernel(
    const float* __restrict__ X, const float* __restrict__ W,
    const float* __restrict__ Bias, float* __restrict__ Z,
    int Cin, int Cfold)
{
    static_assert(NF == 2 * NW, "2 filters per wave");
    static_assert(64 * CH >= SOUT, "chunk covers row");
    constexpr int W2 = 64 * CH + K - 1;     // padded LDS row width
    constexpr int RS = 2 * IPG / PHASES;    // rows staged per phase

    const int t = threadIdx.x;
    // XCD-aware remap (bijective: GRIDJ*64 = 8 xcd * (GRIDJ*8))
    const int lin = blockIdx.x + blockIdx.y * GRIDJ;
    const int xcd = lin & 7;
    const int q   = lin >> 3;
    const int j   = q >> 3;                 // 0..GRIDJ-1
    const int b   = (xcd << 3) + (q & 7);   // all j of b on one xcd
    const int wav = t >> 6, lane = t & 63;

    __shared__ __align__(16) float xs[RS][W2];
    __shared__ __align__(16) float stagebuf[NW][KSEL];

    const float* Xb = X + ((size_t)b * Cin + (size_t)(2 * j) * IPG) * SIN;

    const int f0 = __builtin_amdgcn_readfirstlane(2 * wav);
    float acc0[CH], acc1[CH];
    {
        float bias0 = Bias[2 * j * NF + f0]     + Bias[(2 * j + 1) * NF + f0];
        float bias1 = Bias[2 * j * NF + f0 + 1] + Bias[(2 * j + 1) * NF + f0 + 1];
        #pragma unroll
        for (int i = 0; i < CH; ++i) { acc0[i] = bias0; acc1[i] = bias1; }
    }
    const int base = lane * CH;

    #pragma unroll 1
    for (int ph = 0; ph < PHASES; ++ph) {
        if (ph) __syncthreads();            // prior phase's reads done
        for (int idx = t; idx < RS * W2; idx += NW * 64) {
            int r = idx / W2, p = idx - r * W2;
            int sg = p - (K - 1);
            int gr = ph * RS + r;
            xs[r][p] = (sg >= 0 && sg < SIN) ? Xb[(size_t)gr * SIN + sg] : 0.f;
        }
        __syncthreads();

        int h = (ph * RS) / IPG, c = (ph * RS) % IPG;
        #pragma unroll 1
        for (int r = 0; r < RS; ++r) {
            float win[CH + K - 1];
            #pragma unroll
            for (int p = 0; p < CH + K - 1; ++p)
                win[p] = xs[r][base + p];
            const float* Wp = W + ((size_t)((2 * j + h) * NF + f0) * IPG + c) * K;
            #pragma unroll
            for (int k2 = 0; k2 < K; ++k2) {
                const float w0 = Wp[k2];
                const float w1 = Wp[(size_t)IPG * K + k2];
                #pragma unroll
                for (int i = 0; i < CH; ++i) {
                    acc0[i] = fmaf(win[i + k2], w0, acc0[i]);
                    acc1[i] = fmaf(win[i + k2], w1, acc1[i]);
                }
            }
            if (++c == IPG) { c = 0; ++h; }
        }
    }

    unsigned keys[2][CH];
    #pragma unroll
    for (int i = 0; i < CH; ++i) {
        keys[0][i] = (base + i < SOUT) ? f2ord(acc0[i]) : 0u;
        keys[1][i] = (base + i < SOUT) ? f2ord(acc1[i]) : 0u;
    }
    const size_t orow = (size_t)b * Cfold + (size_t)j * NF;
    float* outs[2] = { Z + (orow + f0) * (size_t)KSEL,
                       Z + (orow + f0 + 1) * (size_t)KSEL };
    wave_selectN_ballot<2, CH>(keys, KSEL, stagebuf[wav], outs);
}

// ---------------------------------------------------------------------------
// FC: (64,352) @ (6,352)^T + b
// ---------------------------------------------------------------------------
__global__ __launch_bounds__(192) void fc_kernel(
    const float* __restrict__ Z, const float* __restrict__ Wf,
    const float* __restrict__ bf, float* __restrict__ out)
{
    int g = blockIdx.x * blockDim.x + threadIdx.x;
    if (g >= 64 * 6) return;
    int b = g / 6, c = g % 6;
    float acc = bf[c];
    const float* zr = Z + b * 352;
    const float* wr = Wf + c * 352;
    for (int i = 0; i < 352; ++i) acc += zr[i] * wr[i];
    out[g] = acc;
}

extern "C" void kernel_launch(void* const* d_in, const int* in_sizes, int n_in,
                              void* d_out, int out_size, void* d_ws, size_t ws_size,
                              hipStream_t stream)
{
    const int*   tokens = (const int*)  d_in[0];
    const float* emb    = (const float*)d_in[1];
    const float* w1     = (const float*)d_in[2];
    const float* b1     = (const float*)d_in[3];
    const float* w2     = (const float*)d_in[4];
    const float* b2     = (const float*)d_in[5];
    const float* w3     = (const float*)d_in[6];
    const float* b3     = (const float*)d_in[7];
    const float* w4     = (const float*)d_in[8];
    const float* b4     = (const float*)d_in[9];
    const float* fcw    = (const float*)d_in[10];
    const float* fcb    = (const float*)d_in[11];
    float* out = (float*)d_out;
    float* ws  = (float*)d_ws;

    // workspace layout (floats) — Z1 no longer exists (fused away):
    //  Z2 [15728640, 23068672)   64*224*512  (29 MB)
    //  Z3 [0,         2359296)   64*144*256
    //  Z4 [2359296,   2381824)   64*88*4
    float* Z2 = ws + 15728640;
    float* Z3 = ws;
    float* Z4 = ws + 2359296;

    // L1+L2 fused: emb gather + pair conv K=7 + fold + top768 + tanh (LDS)
    //              + grouped conv IPG=10 K=5 + fold + top512 + tanh -> Z2
    layer12_fused<<<dim3(16, 64), 896, 0, stream>>>(
        tokens, emb, w1, b1, w2, b2, Z2);

    // L3: IPG=14 NF=18 K=5  512->516, keep 256.  NW=9, CH=9, 2-phase
    //     (LDS 41.7KB -> 3 blocks/CU), XCD swizzle GRIDJ=8
    conv_fold_select_kernel<14, 18, 5, 512, 516, 256, 9, 9, 2, 8>
        <<<dim3(8, 64), 9 * 64, 0, stream>>>(Z2, w3, b3, Z3, 224, 144);

    // L4: IPG=18 NF=22 K=3  256->258, keep 4.  NW=11, CH=5, 1-phase,
    //     XCD swizzle GRIDJ=4
    conv_fold_select_kernel<18, 22, 3, 256, 258, 4, 11, 5, 1, 4>
        <<<dim3(4, 64), 11 * 64, 0, stream>>>(Z3, w4, b4, Z4, 144, 88);

    fc_kernel<<<2, 192, 0, stream>>>(Z4, fcw, fcb, out);
}

// Round 12
// 311.873 us; speedup vs baseline: 1.8172x; 1.0417x over previous
//
#include <hip/hip_runtime.h>
#include <hip/hip_bf16.h>
#include <math.h>

// ---------------------------------------------------------------------------
// DeepDCNN: emb-gather -> 4x [grouped full-conv + pair-fold + ordered top-k +
// tanh] -> FC.  All fp32.
//
// R12 = R7 (310.9us best, absmax 0.0) + two LDS/work removals in layer12:
//  1. stagebuf (28.7KB) removed: the final top-512 select stages into z1,
//     which is DEAD after the ph1 L2 conv (one added barrier).  uni shrinks
//     to xr-only (8.8KB).  LDS 62.4 -> 41.3KB.  Motive: OccupancyPercent has
//     been ~36% on every layer12 variant = ONE resident 14-wave block
//     (14/32=44% peak), not the intended two -- LDS pool suspect.
//  2. z1 zeroing covers only the pad words ([0,4) and [772,836) per row);
//     the value region is fully overwritten by every phase's select.
//
// CLOSED lines (R8-R11): select-count rewrites (DPP/hybrid: VGPR-64 cliff
// spills, 240-700MB scratch; launch_bounds(896,7): 36-VGPR misallocation;
// LDS-histogram radix: exponent-byte bucket skew -> 14.7M bank-conflict
// cycles + absmax drift).  Ballot search + plain launch_bounds stay.
// R1-R7 lesson: only removed instructions/traffic/residency move the clean
// total (power/clock-capped); pipe-shuffling is neutral.
// ---------------------------------------------------------------------------

#if defined(__has_builtin)
#if __has_builtin(__builtin_amdgcn_ballot_w64)
#define BALLOT64(expr) __builtin_amdgcn_ballot_w64(expr)
#endif
#endif
#ifndef BALLOT64
#define BALLOT64(expr) __ballot(expr)
#endif

__device__ __forceinline__ unsigned f2ord(float f) {
    unsigned u = __float_as_uint(f);
    return (u & 0x80000000u) ? ~u : (u | 0x80000000u);
}
__device__ __forceinline__ float ord2f(unsigned key) {
    unsigned u = (key & 0x80000000u) ? (key & 0x7fffffffu) : ~key;
    return __uint_as_float(u);
}
// tanh via exp + hw rcp: 1 - 2*rcp(e^{2x}+1).  |err| ~1e-7.  Keys are
// pre-tanh so selection ordering is unaffected.
__device__ __forceinline__ float tanh_fast(float x) {
    float e = __expf(2.f * x);
    return 1.f - 2.f * __builtin_amdgcn_rcpf(e + 1.f);
}
__device__ __forceinline__ int mbcnt64(unsigned long long m) {
    return __builtin_amdgcn_mbcnt_hi((unsigned)(m >> 32),
           __builtin_amdgcn_mbcnt_lo((unsigned)m, 0u));
}

// ---- compaction + tanh -> stage (LDS) [-> optional coalesced copy-out] ----
// T = threshold key; stable (earliest ties kept), order-preserving.
// COPY=false: kept values land scattered-compacted in stage and stay there
// (used by the fused kernel, stage = conv-input row in LDS).
// COPY=true: float4 copy stage -> out (k multiple of 4; 16B-aligned rows).
template<int CH, bool COPY>
__device__ __forceinline__ void select_finish(const unsigned* keys, unsigned T,
                                              int k, float* stage,
                                              float* __restrict__ out)
{
    int g = 0, e = 0;
    #pragma unroll
    for (int i = 0; i < CH; ++i) { g += (keys[i] > T); e += (keys[i] == T); }

    int gtBefore = 0, eqBefore = 0, totG = 0;
    #pragma unroll
    for (int b = 0; b < 5; ++b) {     // CH <= 17 < 32 -> 5 bits
        unsigned long long mg = BALLOT64((((g >> b) & 1) != 0));
        unsigned long long me = BALLOT64((((e >> b) & 1) != 0));
        gtBefore += mbcnt64(mg) << b;
        eqBefore += mbcnt64(me) << b;
        totG     += __popcll(mg) << b;
    }
    const int needTies = k - totG;    // # of ==T to keep (earliest)

    int gRun = 0, eRun = 0;
    #pragma unroll
    for (int i = 0; i < CH; ++i) {
        const unsigned key = keys[i];
        const bool isG = key > T;
        const bool isE = key == T;
        const int eIdx = eqBefore + eRun;
        const int dst = gtBefore + gRun + min(eIdx, needTies);
        if (isG || (isE && eIdx < needTies))
            stage[dst] = tanh_fast(ord2f(key));
        gRun += isG; eRun += isE;
    }
    if (COPY) {
        // coalesced vectorized copy-out (same-wave DS ordering makes the
        // scatter-write -> contiguous-read sequence safe without barriers)
        const int lane = threadIdx.x & 63;
        const float4* s4 = (const float4*)stage;
        float4* o4 = (float4*)out;
        #pragma unroll 1
        for (int i = lane; i < (k >> 2); i += 64)
            o4[i] = s4[i];
    }
}

// ---- single-row exact top-k (one chain per wave), ballot counting --------
// Lane holds contiguous chunk [lane*CH, ...) of the row as order-keys in
// regs; invalid slots MUST be 0 (all finite-float keys are >= 0x00800000).
template<int CH, bool COPY>
__device__ void wave_select1(const unsigned* keys, int k, float* stage,
                             float* __restrict__ out)
{
    unsigned p = 0u;
    int above = 0, buck = 64 * CH;
    #pragma unroll 1
    for (int pos = 31; pos >= 0; --pos) {
        const unsigned t = p | (1u << pos);
        int c = 0;
        #pragma unroll
        for (int i = 0; i < CH; ++i)
            c += __popcll(BALLOT64((keys[i] >= t)));
        const int inb = c - above;        // bucket members with bit=1
        const int rem = k - above;
        if (inb >= rem) { p = t; buck = inb; }
        else            { above += inb; buck -= inb; }
        if (buck == k - above) break;
    }
    select_finish<CH, COPY>(keys, p, k, stage, out);
}

// ---- N-row exact top-k, interleaved chains (conv L3/L4, N=2) -------------
template<int N, int CH>
__device__ void wave_selectN_ballot(const unsigned (*keys)[CH], int k,
                                    float* stage, float* const* outs)
{
    unsigned p[N];
    int above[N], buck[N];
    #pragma unroll
    for (int n = 0; n < N; ++n) { p[n] = 0u; above[n] = 0; buck[n] = 64 * CH; }

    unsigned doneMask = 0;
    const unsigned allDone = (1u << N) - 1u;
    #pragma unroll 1
    for (int pos = 31; pos >= 0; --pos) {
        #pragma unroll
        for (int n = 0; n < N; ++n) {
            if (!((doneMask >> n) & 1u)) {        // wave-uniform branch
                const unsigned t = p[n] | (1u << pos);
                int c = 0;
                #pragma unroll
                for (int i = 0; i < CH; ++i)
                    c += __popcll(BALLOT64((keys[n][i] >= t)));
                const int inb = c - above[n];
                const int rem = k - above[n];
                if (inb >= rem) { p[n] = t; buck[n] = inb; }
                else            { above[n] += inb; buck[n] -= inb; }
                if (buck[n] == k - above[n]) doneMask |= (1u << n);
            }
        }
        if (doneMask == allDone) break;
    }
    #pragma unroll
    for (int n = 0; n < N; ++n)
        select_finish<CH, true>(keys[n], p[n], k, stage, outs[n]);
}

// ---------------------------------------------------------------------------
// Fused layers 1+2.  grid (16, 64) -> XCD-swizzled to (j2, b), block 896 =
// 14 waves.
// Per block:
//   phase ph=0/1 (L1 group g = 2*j2+ph):
//     - waves 0..9: L1 conv row f1=wav (emb dims 2g,2g+1 from LDS xr),
//       exact top-768 select + tanh written DIRECTLY into z1[wav][4..772)
//     - all 14 waves: L2 partial conv, filter f=wav, input half h=ph
//     - xr restage for ph=1 overlaps the ph=0 accumulation
//   epilogue: barrier (z1 dead), top-512 select per filter staged into z1
//   -> float4 write to Z2.
// LDS: z1 10x836x4 = 33.4 KB + uni(xr[2][1100]) 8.8 KB = 41.3 KB
//      (was 62.4 KB with the dedicated stagebuf; occupancy suspect).
// XCD swizzle: all 16 j2-blocks of batch b land on xcd = b>>3.  Per-XCD emb
// working set 8 b x 1024 tok x 256 B = 2 MB < 4 MB L2 (R6: FETCH 56->8.6MB).
// ---------------------------------------------------------------------------
__global__ __launch_bounds__(896) void layer12_fused(
    const int* __restrict__ tokens, const float* __restrict__ emb,
    const float* __restrict__ W1, const float* __restrict__ B1,
    const float* __restrict__ W2, const float* __restrict__ B2,
    float* __restrict__ Z2)
{
    // XCD-aware remap (bijective: 1024 = 8 xcd * 128)
    const int lin = blockIdx.x + (blockIdx.y << 4);
    const int xcd = lin & 7;
    const int q   = lin >> 3;           // 0..127
    const int j2  = q >> 3;             // 0..15
    const int b   = (xcd << 3) + (q & 7); // 0..63; all j2 of b on one xcd

    const int t  = threadIdx.x;
    const int wav  = t >> 6;            // 0..13
    const int lane = t & 63;

    __shared__ __align__(16) float z1[10][836];
    __shared__ __align__(16) float uni[2 * 1100];   // xr[2][1100]
    float (*xr)[1100] = reinterpret_cast<float (*)[1100]>(uni);
    const float2* emb2 = (const float2*)emb;

    // zero ONLY the pad words: [0,4) and [772,836) per row (68 words x 10
    // rows).  The value region [4,772) is fully overwritten by each phase's
    // select before any read.
    for (int i = t; i < 680; i += 896) {
        const int r = i / 68;
        const int w = i - r * 68;
        z1[r][(w < 4) ? w : (768 + w)] = 0.f;
    }

    // L2 accumulator: filter f = wav, bias = folded pair of halves
    const int f = __builtin_amdgcn_readfirstlane(wav);
    float acc[13];
    {
        const float bias = B2[(2 * j2) * 14 + f] + B2[(2 * j2 + 1) * 14 + f];
        #pragma unroll
        for (int i = 0; i < 13; ++i) acc[i] = bias;
    }
    const int base = lane * 13;

    // stage xr for phase 0 (L1 group g = 2*j2; emb dim pair g)
    {
        const int g = 2 * j2;
        for (int i = t; i < 1100; i += 896) {
            int s = i - 6; float a = 0.f, c = 0.f;
            if (s >= 0 && s < 1024) {
                int tok = tokens[b * 1024 + s];
                float2 v = emb2[(size_t)tok * 32 + g];
                a = v.x; c = v.y;
            }
            xr[0][i] = a; xr[1][i] = c;
        }
    }
    __syncthreads();   // xr(0) + z1 pad zeros visible

    #pragma unroll 1
    for (int ph = 0; ph < 2; ++ph) {
        const int g = 2 * j2 + ph;

        // ---- L1: conv + select + tanh -> z1 row (waves 0..9) ----
        if (wav < 10) {
            const int f1 = wav;
            float wa[7], wb[7];
            #pragma unroll
            for (int k2 = 0; k2 < 7; ++k2) {
                wa[k2] = W1[(2 * g * 10 + f1) * 7 + k2];
                wb[k2] = W1[((2 * g + 1) * 10 + f1) * 7 + k2];
            }
            const float bias1 = B1[2 * g * 10 + f1] + B1[(2 * g + 1) * 10 + f1];
            const int beg = lane * 17;
            unsigned keys1[17];
            #pragma unroll
            for (int i = 0; i < 17; ++i) {
                float a1 = bias1;
                #pragma unroll
                for (int k2 = 0; k2 < 7; ++k2)
                    a1 += xr[0][beg + i + k2] * wa[k2]
                        + xr[1][beg + i + k2] * wb[k2];
                keys1[i] = (beg + i < 1030) ? f2ord(a1) : 0u;
            }
            wave_select1<17, false>(keys1, 768, &z1[wav][4], nullptr);
        }
        __syncthreads();   // z1(ph) ready; all xr reads of this phase done

        if (ph == 0) {
            // restage xr for phase 1 — overlaps the h=0 accumulation below
            const int g1 = 2 * j2 + 1;
            for (int i = t; i < 1100; i += 896) {
                int s = i - 6; float a = 0.f, c = 0.f;
                if (s >= 0 && s < 1024) {
                    int tok = tokens[b * 1024 + s];
                    float2 v = emb2[(size_t)tok * 32 + g1];
                    a = v.x; c = v.y;
                }
                xr[0][i] = a; xr[1][i] = c;
            }
        }

        // ---- L2 partial conv: all 14 waves, filter f, half h=ph ----
        {
            const float* Wp0 = W2 + (size_t)((2 * j2 + ph) * 14 + f) * 10 * 5;
            #pragma unroll 1
            for (int r = 0; r < 10; ++r) {
                float win[17];
                #pragma unroll
                for (int p = 0; p < 17; ++p) win[p] = z1[r][base + p];
                const float* Wp = Wp0 + r * 5;
                #pragma unroll
                for (int k2 = 0; k2 < 5; ++k2) {
                    const float w0 = Wp[k2];
                    #pragma unroll
                    for (int i = 0; i < 13; ++i)
                        acc[i] = fmaf(win[i + k2], w0, acc[i]);
                }
            }
        }
        if (ph == 0) __syncthreads();  // xr(1) staged & z1(0) fully consumed
    }

    // ---- L2 select: one chain per wave, k=512, staged into DEAD z1 ----
    // Barrier: every wave must finish its h=1 conv reads of z1 before any
    // wave overwrites z1 with its stage data.
    __syncthreads();
    unsigned keys2[13];
    #pragma unroll
    for (int i = 0; i < 13; ++i)
        keys2[i] = (base + i < 772) ? f2ord(acc[i]) : 0u;
    float* stage = ((float*)z1) + wav * 512;   // 14*512 = 7168 <= 8360 words
    float* outp = Z2 + ((size_t)b * 224 + (size_t)j2 * 14 + f) * 512;
    wave_select1<13, true>(keys2, 512, stage, outp);
}

// ---------------------------------------------------------------------------
// Fused conv + fold + select + tanh (layers 3-4).
// grid (GRIDJ j, 64 b) -> XCD-swizzled so all j-blocks of batch b land on
// xcd = b>>3 (matches layer12's Z2/Z3 placement -> producer-L2 hits).
// Wave w computes output rows (filters) f = 2w, 2w+1 (length SOUT), then
// dual-chain selects top-KSEL of each.
// ---------------------------------------------------------------------------
template <int IPG, int NF, int K, int SIN, int SOUT, int KSEL, int NW, int CH,
          int PHASES, int GRIDJ>
__global__ __launch_bounds__(NW * 64) void conv_fold_select_kernel(
    const float* __restrict__ X, const float* __restrict__ W,
    const float* __restrict__ Bias, float* __restrict__ Z,
    int Cin, int Cfold)
{
    static_assert(NF == 2 * NW, "2 filters per wave");
    static_assert(64 * CH >= SOUT, "chunk covers row");
    constexpr int W2 = 64 * CH + K - 1;     // padded LDS row width
    constexpr int RS = 2 * IPG / PHASES;    // rows staged per phase

    const int t = threadIdx.x;
    // XCD-aware remap (bijective: GRIDJ*64 = 8 xcd * (GRIDJ*8))
    const int lin = blockIdx.x + blockIdx.y * GRIDJ;
    const int xcd = lin & 7;
    const int q   = lin >> 3;
    const int j   = q >> 3;                 // 0..GRIDJ-1
    const int b   = (xcd << 3) + (q & 7);   // all j of b on one xcd
    const int wav = t >> 6, lane = t & 63;

    __shared__ __align__(16) float xs[RS][W2];
    __shared__ __align__(16) float stagebuf[NW][KSEL];

    const float* Xb = X + ((size_t)b * Cin + (size_t)(2 * j) * IPG) * SIN;

    const int f0 = __builtin_amdgcn_readfirstlane(2 * wav);
    float acc0[CH], acc1[CH];
    {
        float bias0 = Bias[2 * j * NF + f0]     + Bias[(2 * j + 1) * NF + f0];
        float bias1 = Bias[2 * j * NF + f0 + 1] + Bias[(2 * j + 1) * NF + f0 + 1];
        #pragma unroll
        for (int i = 0; i < CH; ++i) { acc0[i] = bias0; acc1[i] = bias1; }
    }
    const int base = lane * CH;

    #pragma unroll 1
    for (int ph = 0; ph < PHASES; ++ph) {
        if (ph) __syncthreads();            // prior phase's reads done
        for (int idx = t; idx < RS * W2; idx += NW * 64) {
            int r = idx / W2, p = idx - r * W2;
            int sg = p - (K - 1);
            int gr = ph * RS + r;
            xs[r][p] = (sg >= 0 && sg < SIN) ? Xb[(size_t)gr * SIN + sg] : 0.f;
        }
        __syncthreads();

        int h = (ph * RS) / IPG, c = (ph * RS) % IPG;
        #pragma unroll 1
        for (int r = 0; r < RS; ++r) {
            float win[CH + K - 1];
            #pragma unroll
            for (int p = 0; p < CH + K - 1; ++p)
                win[p] = xs[r][base + p];
            const float* Wp = W + ((size_t)((2 * j + h) * NF + f0) * IPG + c) * K;
            #pragma unroll
            for (int k2 = 0; k2 < K; ++k2) {
                const float w0 = Wp[k2];
                const float w1 = Wp[(size_t)IPG * K + k2];
                #pragma unroll
                for (int i = 0; i < CH; ++i) {
                    acc0[i] = fmaf(win[i + k2], w0, acc0[i]);
                    acc1[i] = fmaf(win[i + k2], w1, acc1[i]);
                }
            }
            if (++c == IPG) { c = 0; ++h; }
        }
    }

    unsigned keys[2][CH];
    #pragma unroll
    for (int i = 0; i < CH; ++i) {
        keys[0][i] = (base + i < SOUT) ? f2ord(acc0[i]) : 0u;
        keys[1][i] = (base + i < SOUT) ? f2ord(acc1[i]) : 0u;
    }
    const size_t orow = (size_t)b * Cfold + (size_t)j * NF;
    float* outs[2] = { Z + (orow + f0) * (size_t)KSEL,
                       Z + (orow + f0 + 1) * (size_t)KSEL };
    wave_selectN_ballot<2, CH>(keys, KSEL, stagebuf[wav], outs);
}

// ---------------------------------------------------------------------------
// FC: (64,352) @ (6,352)^T + b
// ---------------------------------------------------------------------------
__global__ __launch_bounds__(192) void fc_kernel(
    const float* __restrict__ Z, const float* __restrict__ Wf,
    const float* __restrict__ bf, float* __restrict__ out)
{
    int g = blockIdx.x * blockDim.x + threadIdx.x;
    if (g >= 64 * 6) return;
    int b = g / 6, c = g % 6;
    float acc = bf[c];
    const float* zr = Z + b * 352;
    const float* wr = Wf + c * 352;
    for (int i = 0; i < 352; ++i) acc += zr[i] * wr[i];
    out[g] = acc;
}

extern "C" void kernel_launch(void* const* d_in, const int* in_sizes, int n_in,
                              void* d_out, int out_size, void* d_ws, size_t ws_size,
                              hipStream_t stream)
{
    const int*   tokens = (const int*)  d_in[0];
    const float* emb    = (const float*)d_in[1];
    const float* w1     = (const float*)d_in[2];
    const float* b1     = (const float*)d_in[3];
    const float* w2     = (const float*)d_in[4];
    const float* b2     = (const float*)d_in[5];
    const float* w3     = (const float*)d_in[6];
    const float* b3     = (const float*)d_in[7];
    const float* w4     = (const float*)d_in[8];
    const float* b4     = (const float*)d_in[9];
    const float* fcw    = (const float*)d_in[10];
    const float* fcb    = (const float*)d_in[11];
    float* out = (float*)d_out;
    float* ws  = (float*)d_ws;

    // workspace layout (floats) — Z1 no longer exists (fused away):
    //  Z2 [15728640, 23068672)   64*224*512  (29 MB)
    //  Z3 [0,         2359296)   64*144*256
    //  Z4 [2359296,   2381824)   64*88*4
    float* Z2 = ws + 15728640;
    float* Z3 = ws;
    float* Z4 = ws + 2359296;

    // L1+L2 fused: emb gather + pair conv K=7 + fold + top768 + tanh (LDS)
    //              + grouped conv IPG=10 K=5 + fold + top512 + tanh -> Z2
    layer12_fused<<<dim3(16, 64), 896, 0, stream>>>(
        tokens, emb, w1, b1, w2, b2, Z2);

    // L3: IPG=14 NF=18 K=5  512->516, keep 256.  NW=9, CH=9, 2-phase
    //     (LDS 41.7KB -> 3 blocks/CU), XCD swizzle GRIDJ=8
    conv_fold_select_kernel<14, 18, 5, 512, 516, 256, 9, 9, 2, 8>
        <<<dim3(8, 64), 9 * 64, 0, stream>>>(Z2, w3, b3, Z3, 224, 144);

    // L4: IPG=18 NF=22 K=3  256->258, keep 4.  NW=11, CH=5, 1-phase,
    //     XCD swizzle GRIDJ=4
    conv_fold_select_kernel<18, 22, 3, 256, 258, 4, 11, 5, 1, 4>
        <<<dim3(4, 64), 11 * 64, 0, stream>>>(Z3, w4, b4, Z4, 144, 88);

    fc_kernel<<<2, 192, 0, stream>>>(Z4, fcw, fcb, out);
}

// Round 13
// 309.674 us; speedup vs baseline: 1.8301x; 1.0071x over previous
//
#include <hip/hip_runtime.h>
#include <hip/hip_bf16.h>
#include <math.h>

// ---------------------------------------------------------------------------
// DeepDCNN: emb-gather -> 4x [grouped full-conv + pair-fold + ordered top-k +
// tanh] -> FC.  All fp32.
//
// R13 = R12 (311.9us, absmax 0.0) + L3 LDS shrink to test the 64KB-pool
// hypothesis: OccupancyPercent has been ~37% (= ONE 14-wave block) for
// layer12 at BOTH 62.4KB and 41.3KB LDS, though nominal limits allow two.
// Consistent explanation: usable LDS scheduling pool ~64KB/CU, so any block
// >32KB runs solo.  L3 (41.7KB) would then be at 1 block = 9 waves = 28%.
// Changes (tail only; layer12 untouched):
//  - L3 PHASES 2->4: xs = 7x580x4 = 16.2KB.  Phases partition the row walk
//    sequentially -> FMA order bit-identical.
//  - conv template: stagebuf removed; selects stage into xs (dead after the
//    conv) behind one added barrier (same dead-buffer reuse as R12's z1,
//    which held absmax 0.0).  L3 LDS 41.7 -> 16.3KB; L4 46.6 -> 46.4KB.
//
// CLOSED lines: select-count rewrites (R8-R10 regalloc-cliff spills),
// LDS-histogram radix (R11 bank conflicts + drift), layer12 LDS-occupancy
// (R12 null).  R1-R7: only removed instructions/traffic/residency move the
// clean total (power/clock-capped); pipe-shuffling is neutral.
// ---------------------------------------------------------------------------

#if defined(__has_builtin)
#if __has_builtin(__builtin_amdgcn_ballot_w64)
#define BALLOT64(expr) __builtin_amdgcn_ballot_w64(expr)
#endif
#endif
#ifndef BALLOT64
#define BALLOT64(expr) __ballot(expr)
#endif

__device__ __forceinline__ unsigned f2ord(float f) {
    unsigned u = __float_as_uint(f);
    return (u & 0x80000000u) ? ~u : (u | 0x80000000u);
}
__device__ __forceinline__ float ord2f(unsigned key) {
    unsigned u = (key & 0x80000000u) ? (key & 0x7fffffffu) : ~key;
    return __uint_as_float(u);
}
// tanh via exp + hw rcp: 1 - 2*rcp(e^{2x}+1).  |err| ~1e-7.  Keys are
// pre-tanh so selection ordering is unaffected.
__device__ __forceinline__ float tanh_fast(float x) {
    float e = __expf(2.f * x);
    return 1.f - 2.f * __builtin_amdgcn_rcpf(e + 1.f);
}
__device__ __forceinline__ int mbcnt64(unsigned long long m) {
    return __builtin_amdgcn_mbcnt_hi((unsigned)(m >> 32),
           __builtin_amdgcn_mbcnt_lo((unsigned)m, 0u));
}

// ---- compaction + tanh -> stage (LDS) [-> optional coalesced copy-out] ----
// T = threshold key; stable (earliest ties kept), order-preserving.
// COPY=false: kept values land scattered-compacted in stage and stay there
// (used by the fused kernel, stage = conv-input row in LDS).
// COPY=true: float4 copy stage -> out (k multiple of 4; 16B-aligned rows).
template<int CH, bool COPY>
__device__ __forceinline__ void select_finish(const unsigned* keys, unsigned T,
                                              int k, float* stage,
                                              float* __restrict__ out)
{
    int g = 0, e = 0;
    #pragma unroll
    for (int i = 0; i < CH; ++i) { g += (keys[i] > T); e += (keys[i] == T); }

    int gtBefore = 0, eqBefore = 0, totG = 0;
    #pragma unroll
    for (int b = 0; b < 5; ++b) {     // CH <= 17 < 32 -> 5 bits
        unsigned long long mg = BALLOT64((((g >> b) & 1) != 0));
        unsigned long long me = BALLOT64((((e >> b) & 1) != 0));
        gtBefore += mbcnt64(mg) << b;
        eqBefore += mbcnt64(me) << b;
        totG     += __popcll(mg) << b;
    }
    const int needTies = k - totG;    // # of ==T to keep (earliest)

    int gRun = 0, eRun = 0;
    #pragma unroll
    for (int i = 0; i < CH; ++i) {
        const unsigned key = keys[i];
        const bool isG = key > T;
        const bool isE = key == T;
        const int eIdx = eqBefore + eRun;
        const int dst = gtBefore + gRun + min(eIdx, needTies);
        if (isG || (isE && eIdx < needTies))
            stage[dst] = tanh_fast(ord2f(key));
        gRun += isG; eRun += isE;
    }
    if (COPY) {
        // coalesced vectorized copy-out (same-wave DS ordering makes the
        // scatter-write -> contiguous-read sequence safe without barriers)
        const int lane = threadIdx.x & 63;
        const float4* s4 = (const float4*)stage;
        float4* o4 = (float4*)out;
        #pragma unroll 1
        for (int i = lane; i < (k >> 2); i += 64)
            o4[i] = s4[i];
    }
}

// ---- single-row exact top-k (one chain per wave), ballot counting --------
// Lane holds contiguous chunk [lane*CH, ...) of the row as order-keys in
// regs; invalid slots MUST be 0 (all finite-float keys are >= 0x00800000).
template<int CH, bool COPY>
__device__ void wave_select1(const unsigned* keys, int k, float* stage,
                             float* __restrict__ out)
{
    unsigned p = 0u;
    int above = 0, buck = 64 * CH;
    #pragma unroll 1
    for (int pos = 31; pos >= 0; --pos) {
        const unsigned t = p | (1u << pos);
        int c = 0;
        #pragma unroll
        for (int i = 0; i < CH; ++i)
            c += __popcll(BALLOT64((keys[i] >= t)));
        const int inb = c - above;        // bucket members with bit=1
        const int rem = k - above;
        if (inb >= rem) { p = t; buck = inb; }
        else            { above += inb; buck -= inb; }
        if (buck == k - above) break;
    }
    select_finish<CH, COPY>(keys, p, k, stage, out);
}

// ---- N-row exact top-k, interleaved chains (conv L3/L4, N=2) -------------
template<int N, int CH>
__device__ void wave_selectN_ballot(const unsigned (*keys)[CH], int k,
                                    float* stage, float* const* outs)
{
    unsigned p[N];
    int above[N], buck[N];
    #pragma unroll
    for (int n = 0; n < N; ++n) { p[n] = 0u; above[n] = 0; buck[n] = 64 * CH; }

    unsigned doneMask = 0;
    const unsigned allDone = (1u << N) - 1u;
    #pragma unroll 1
    for (int pos = 31; pos >= 0; --pos) {
        #pragma unroll
        for (int n = 0; n < N; ++n) {
            if (!((doneMask >> n) & 1u)) {        // wave-uniform branch
                const unsigned t = p[n] | (1u << pos);
                int c = 0;
                #pragma unroll
                for (int i = 0; i < CH; ++i)
                    c += __popcll(BALLOT64((keys[n][i] >= t)));
                const int inb = c - above[n];
                const int rem = k - above[n];
                if (inb >= rem) { p[n] = t; buck[n] = inb; }
                else            { above[n] += inb; buck[n] -= inb; }
                if (buck[n] == k - above[n]) doneMask |= (1u << n);
            }
        }
        if (doneMask == allDone) break;
    }
    #pragma unroll
    for (int n = 0; n < N; ++n)
        select_finish<CH, true>(keys[n], p[n], k, stage, outs[n]);
}

// ---------------------------------------------------------------------------
// Fused layers 1+2.  grid (16, 64) -> XCD-swizzled to (j2, b), block 896 =
// 14 waves.  (Unchanged from R12: 164.5us, absmax 0.0.)
// LDS: z1 10x836x4 = 33.4 KB + uni(xr[2][1100]) 8.8 KB = 41.3 KB.
// XCD swizzle: all 16 j2-blocks of batch b land on xcd = b>>3.  Per-XCD emb
// working set 8 b x 1024 tok x 256 B = 2 MB < 4 MB L2 (R6: FETCH 56->8.6MB).
// ---------------------------------------------------------------------------
__global__ __launch_bounds__(896) void layer12_fused(
    const int* __restrict__ tokens, const float* __restrict__ emb,
    const float* __restrict__ W1, const float* __restrict__ B1,
    const float* __restrict__ W2, const float* __restrict__ B2,
    float* __restrict__ Z2)
{
    // XCD-aware remap (bijective: 1024 = 8 xcd * 128)
    const int lin = blockIdx.x + (blockIdx.y << 4);
    const int xcd = lin & 7;
    const int q   = lin >> 3;           // 0..127
    const int j2  = q >> 3;             // 0..15
    const int b   = (xcd << 3) + (q & 7); // 0..63; all j2 of b on one xcd

    const int t  = threadIdx.x;
    const int wav  = t >> 6;            // 0..13
    const int lane = t & 63;

    __shared__ __align__(16) float z1[10][836];
    __shared__ __align__(16) float uni[2 * 1100];   // xr[2][1100]
    float (*xr)[1100] = reinterpret_cast<float (*)[1100]>(uni);
    const float2* emb2 = (const float2*)emb;

    // zero ONLY the pad words: [0,4) and [772,836) per row (68 words x 10
    // rows).  The value region [4,772) is fully overwritten by each phase's
    // select before any read.
    for (int i = t; i < 680; i += 896) {
        const int r = i / 68;
        const int w = i - r * 68;
        z1[r][(w < 4) ? w : (768 + w)] = 0.f;
    }

    // L2 accumulator: filter f = wav, bias = folded pair of halves
    const int f = __builtin_amdgcn_readfirstlane(wav);
    float acc[13];
    {
        const float bias = B2[(2 * j2) * 14 + f] + B2[(2 * j2 + 1) * 14 + f];
        #pragma unroll
        for (int i = 0; i < 13; ++i) acc[i] = bias;
    }
    const int base = lane * 13;

    // stage xr for phase 0 (L1 group g = 2*j2; emb dim pair g)
    {
        const int g = 2 * j2;
        for (int i = t; i < 1100; i += 896) {
            int s = i - 6; float a = 0.f, c = 0.f;
            if (s >= 0 && s < 1024) {
                int tok = tokens[b * 1024 + s];
                float2 v = emb2[(size_t)tok * 32 + g];
                a = v.x; c = v.y;
            }
            xr[0][i] = a; xr[1][i] = c;
        }
    }
    __syncthreads();   // xr(0) + z1 pad zeros visible

    #pragma unroll 1
    for (int ph = 0; ph < 2; ++ph) {
        const int g = 2 * j2 + ph;

        // ---- L1: conv + select + tanh -> z1 row (waves 0..9) ----
        if (wav < 10) {
            const int f1 = wav;
            float wa[7], wb[7];
            #pragma unroll
            for (int k2 = 0; k2 < 7; ++k2) {
                wa[k2] = W1[(2 * g * 10 + f1) * 7 + k2];
                wb[k2] = W1[((2 * g + 1) * 10 + f1) * 7 + k2];
            }
            const float bias1 = B1[2 * g * 10 + f1] + B1[(2 * g + 1) * 10 + f1];
            const int beg = lane * 17;
            unsigned keys1[17];
            #pragma unroll
            for (int i = 0; i < 17; ++i) {
                float a1 = bias1;
                #pragma unroll
                for (int k2 = 0; k2 < 7; ++k2)
                    a1 += xr[0][beg + i + k2] * wa[k2]
                        + xr[1][beg + i + k2] * wb[k2];
                keys1[i] = (beg + i < 1030) ? f2ord(a1) : 0u;
            }
            wave_select1<17, false>(keys1, 768, &z1[wav][4], nullptr);
        }
        __syncthreads();   // z1(ph) ready; all xr reads of this phase done

        if (ph == 0) {
            // restage xr for phase 1 — overlaps the h=0 accumulation below
            const int g1 = 2 * j2 + 1;
            for (int i = t; i < 1100; i += 896) {
                int s = i - 6; float a = 0.f, c = 0.f;
                if (s >= 0 && s < 1024) {
                    int tok = tokens[b * 1024 + s];
                    float2 v = emb2[(size_t)tok * 32 + g1];
                    a = v.x; c = v.y;
                }
                xr[0][i] = a; xr[1][i] = c;
            }
        }

        // ---- L2 partial conv: all 14 waves, filter f, half h=ph ----
        {
            const float* Wp0 = W2 + (size_t)((2 * j2 + ph) * 14 + f) * 10 * 5;
            #pragma unroll 1
            for (int r = 0; r < 10; ++r) {
                float win[17];
                #pragma unroll
                for (int p = 0; p < 17; ++p) win[p] = z1[r][base + p];
                const float* Wp = Wp0 + r * 5;
                #pragma unroll
                for (int k2 = 0; k2 < 5; ++k2) {
                    const float w0 = Wp[k2];
                    #pragma unroll
                    for (int i = 0; i < 13; ++i)
                        acc[i] = fmaf(win[i + k2], w0, acc[i]);
                }
            }
        }
        if (ph == 0) __syncthreads();  // xr(1) staged & z1(0) fully consumed
    }

    // ---- L2 select: one chain per wave, k=512, staged into DEAD z1 ----
    // Barrier: every wave must finish its h=1 conv reads of z1 before any
    // wave overwrites z1 with its stage data.
    __syncthreads();
    unsigned keys2[13];
    #pragma unroll
    for (int i = 0; i < 13; ++i)
        keys2[i] = (base + i < 772) ? f2ord(acc[i]) : 0u;
    float* stage = ((float*)z1) + wav * 512;   // 14*512 = 7168 <= 8360 words
    float* outp = Z2 + ((size_t)b * 224 + (size_t)j2 * 14 + f) * 512;
    wave_select1<13, true>(keys2, 512, stage, outp);
}

// ---------------------------------------------------------------------------
// Fused conv + fold + select + tanh (layers 3-4).
// grid (GRIDJ j, 64 b) -> XCD-swizzled so all j-blocks of batch b land on
// xcd = b>>3 (matches layer12's Z2/Z3 placement -> producer-L2 hits).
// Wave w computes output rows (filters) f = 2w, 2w+1 (length SOUT), then
// dual-chain selects top-KSEL of each, staged into xs (DEAD after the conv;
// barrier before reuse).  No dedicated stagebuf -> L3 LDS 41.7 -> 16.3KB.
// ---------------------------------------------------------------------------
template <int IPG, int NF, int K, int SIN, int SOUT, int KSEL, int NW, int CH,
          int PHASES, int GRIDJ>
__global__ __launch_bounds__(NW * 64) void conv_fold_select_kernel(
    const float* __restrict__ X, const float* __restrict__ W,
    const float* __restrict__ Bias, float* __restrict__ Z,
    int Cin, int Cfold)
{
    static_assert(NF == 2 * NW, "2 filters per wave");
    static_assert(64 * CH >= SOUT, "chunk covers row");
    constexpr int W2 = 64 * CH + K - 1;     // padded LDS row width
    constexpr int RS = 2 * IPG / PHASES;    // rows staged per phase
    static_assert(NW * KSEL <= RS * W2, "stage region fits in xs");

    const int t = threadIdx.x;
    // XCD-aware remap (bijective: GRIDJ*64 = 8 xcd * (GRIDJ*8))
    const int lin = blockIdx.x + blockIdx.y * GRIDJ;
    const int xcd = lin & 7;
    const int q   = lin >> 3;
    const int j   = q >> 3;                 // 0..GRIDJ-1
    const int b   = (xcd << 3) + (q & 7);   // all j of b on one xcd
    const int wav = t >> 6, lane = t & 63;

    __shared__ __align__(16) float xs[RS][W2];

    const float* Xb = X + ((size_t)b * Cin + (size_t)(2 * j) * IPG) * SIN;

    const int f0 = __builtin_amdgcn_readfirstlane(2 * wav);
    float acc0[CH], acc1[CH];
    {
        float bias0 = Bias[2 * j * NF + f0]     + Bias[(2 * j + 1) * NF + f0];
        float bias1 = Bias[2 * j * NF + f0 + 1] + Bias[(2 * j + 1) * NF + f0 + 1];
        #pragma unroll
        for (int i = 0; i < CH; ++i) { acc0[i] = bias0; acc1[i] = bias1; }
    }
    const int base = lane * CH;

    #pragma unroll 1
    for (int ph = 0; ph < PHASES; ++ph) {
        if (ph) __syncthreads();            // prior phase's reads done
        for (int idx = t; idx < RS * W2; idx += NW * 64) {
            int r = idx / W2, p = idx - r * W2;
            int sg = p - (K - 1);
            int gr = ph * RS + r;
            xs[r][p] = (sg >= 0 && sg < SIN) ? Xb[(size_t)gr * SIN + sg] : 0.f;
        }
        __syncthreads();

        int h = (ph * RS) / IPG, c = (ph * RS) % IPG;
        #pragma unroll 1
        for (int r = 0; r < RS; ++r) {
            float win[CH + K - 1];
            #pragma unroll
            for (int p = 0; p < CH + K - 1; ++p)
                win[p] = xs[r][base + p];
            const float* Wp = W + ((size_t)((2 * j + h) * NF + f0) * IPG + c) * K;
            #pragma unroll
            for (int k2 = 0; k2 < K; ++k2) {
                const float w0 = Wp[k2];
                const float w1 = Wp[(size_t)IPG * K + k2];
                #pragma unroll
                for (int i = 0; i < CH; ++i) {
                    acc0[i] = fmaf(win[i + k2], w0, acc0[i]);
                    acc1[i] = fmaf(win[i + k2], w1, acc1[i]);
                }
            }
            if (++c == IPG) { c = 0; ++h; }
        }
    }

    // xs is dead now (all conv reads done); barrier, then reuse as stage.
    __syncthreads();

    unsigned keys[2][CH];
    #pragma unroll
    for (int i = 0; i < CH; ++i) {
        keys[0][i] = (base + i < SOUT) ? f2ord(acc0[i]) : 0u;
        keys[1][i] = (base + i < SOUT) ? f2ord(acc1[i]) : 0u;
    }
    const size_t orow = (size_t)b * Cfold + (size_t)j * NF;
    float* outs[2] = { Z + (orow + f0) * (size_t)KSEL,
                       Z + (orow + f0 + 1) * (size_t)KSEL };
    float* stage = ((float*)xs) + wav * KSEL;
    wave_selectN_ballot<2, CH>(keys, KSEL, stage, outs);
}

// ---------------------------------------------------------------------------
// FC: (64,352) @ (6,352)^T + b
// ---------------------------------------------------------------------------
__global__ __launch_bounds__(192) void fc_kernel(
    const float* __restrict__ Z, const float* __restrict__ Wf,
    const float* __restrict__ bf, float* __restrict__ out)
{
    int g = blockIdx.x * blockDim.x + threadIdx.x;
    if (g >= 64 * 6) return;
    int b = g / 6, c = g % 6;
    float acc = bf[c];
    const float* zr = Z + b * 352;
    const float* wr = Wf + c * 352;
    for (int i = 0; i < 352; ++i) acc += zr[i] * wr[i];
    out[g] = acc;
}

extern "C" void kernel_launch(void* const* d_in, const int* in_sizes, int n_in,
                              void* d_out, int out_size, void* d_ws, size_t ws_size,
                              hipStream_t stream)
{
    const int*   tokens = (const int*)  d_in[0];
    const float* emb    = (const float*)d_in[1];
    const float* w1     = (const float*)d_in[2];
    const float* b1     = (const float*)d_in[3];
    const float* w2     = (const float*)d_in[4];
    const float* b2     = (const float*)d_in[5];
    const float* w3     = (const float*)d_in[6];
    const float* b3     = (const float*)d_in[7];
    const float* w4     = (const float*)d_in[8];
    const float* b4     = (const float*)d_in[9];
    const float* fcw    = (const float*)d_in[10];
    const float* fcb    = (const float*)d_in[11];
    float* out = (float*)d_out;
    float* ws  = (float*)d_ws;

    // workspace layout (floats) — Z1 no longer exists (fused away):
    //  Z2 [15728640, 23068672)   64*224*512  (29 MB)
    //  Z3 [0,         2359296)   64*144*256
    //  Z4 [2359296,   2381824)   64*88*4
    float* Z2 = ws + 15728640;
    float* Z3 = ws;
    float* Z4 = ws + 2359296;

    // L1+L2 fused: emb gather + pair conv K=7 + fold + top768 + tanh (LDS)
    //              + grouped conv IPG=10 K=5 + fold + top512 + tanh -> Z2
    layer12_fused<<<dim3(16, 64), 896, 0, stream>>>(
        tokens, emb, w1, b1, w2, b2, Z2);

    // L3: IPG=14 NF=18 K=5  512->516, keep 256.  NW=9, CH=9, 4-phase
    //     (xs 7x580x4 = 16.2KB; stage reuses xs), XCD swizzle GRIDJ=8
    conv_fold_select_kernel<14, 18, 5, 512, 516, 256, 9, 9, 4, 8>
        <<<dim3(8, 64), 9 * 64, 0, stream>>>(Z2, w3, b3, Z3, 224, 144);

    // L4: IPG=18 NF=22 K=3  256->258, keep 4.  NW=11, CH=5, 1-phase,
    //     XCD swizzle GRIDJ=4 (stage reuses xs; LDS 46.4KB)
    conv_fold_select_kernel<18, 22, 3, 256, 258, 4, 11, 5, 1, 4>
        <<<dim3(4, 64), 11 * 64, 0, stream>>>(Z3, w4, b4, Z4, 144, 88);

    fc_kernel<<<2, 192, 0, stream>>>(Z4, fcw, fcb, out);
}